// Round 21
// baseline (256.076 us; speedup 1.0000x reference)
//
#include <hip/hip_runtime.h>

#define NDIM 128
#define BKT_SHIFT 9            // 512 nodes per bucket
#define BKT_NODES 512
#define BKT_CAP   12288        // edges capacity per bucket (mean ~8163)
#define PART_CHUNK 4096        // edges per block in partition kernel

typedef unsigned short u16;
typedef unsigned char u8;
typedef unsigned int u32;
typedef __attribute__((ext_vector_type(8))) short bf16x8;
typedef __attribute__((ext_vector_type(4))) float f32x4;
typedef __attribute__((ext_vector_type(2))) float f32x2;

__device__ inline u16 f2bf(float f) {
    u32 u = __float_as_uint(f);
    u += 0x7fffu + ((u >> 16) & 1u);   // RNE
    return (u16)(u >> 16);
}
__device__ inline float bf2f(u16 h) { return __uint_as_float((u32)h << 16); }

// float -> fp8 e4m3fn (OCP), RNE, saturating.
__device__ inline u8 f2q(float f) {
    u32 u = __float_as_uint(f);
    u32 s = (u >> 24) & 0x80u;
    float a = __uint_as_float(u & 0x7fffffffu);
    if (a < 0.015625f)
        return (u8)(s | (u32)__float2int_rn(a * 512.f));
    if (a >= 448.f) return (u8)(s | 0x7Eu);
    u32 ur = (u & 0x7fffffffu) + 0x7FFFFu + ((u >> 20) & 1u);
    int e = (int)(ur >> 23) - 127;
    u32 man = (ur >> 20) & 7u;
    u32 r = ((u32)(e + 7) << 3) | man;
    if (r > 0x7Eu) r = 0x7Eu;
    return (u8)(s | r);
}

#if __has_builtin(__builtin_amdgcn_cvt_pk_f32_fp8)
template<bool HI>
__device__ inline f32x2 dq2(u32 w) {
    return __builtin_amdgcn_cvt_pk_f32_fp8((int)w, HI);
}
#else
__device__ inline float dq1(u32 b) {
    int e = (b >> 3) & 15, m = b & 7, s = (b >> 7) & 1;
    int norm = e ? 1 : 0;
    float f = (float)(m + (norm << 3));
    float sc = __uint_as_float((u32)(((e ? e : 1) - 10) + 127) << 23);
    float v = f * sc;
    return s ? -v : v;
}
template<bool HI>
__device__ inline f32x2 dq2(u32 w) {
    u32 sh = HI ? 16 : 0;
    f32x2 r; r.x = dq1((w >> sh) & 0xff); r.y = dq1((w >> (sh + 8)) & 0xff);
    return r;
}
#endif

// ---------------- bucketed CSR build (unchanged — working) ----------------

__global__ __launch_bounds__(256) void partition_kernel(
    const int* __restrict__ ei, int E,
    int* __restrict__ gcur, u32* __restrict__ ebuf) {
    __shared__ int hcnt[256];
    __shared__ int hbase[256];
    const int tid = threadIdx.x;
    const int base = blockIdx.x * PART_CHUNK;
    hcnt[tid] = 0;
    __syncthreads();

    u32 val[16];
    int bkt[16];
    #pragma unroll
    for (int k = 0; k < 16; ++k) {
        int e = base + k * 256 + tid;
        bkt[k] = -1;
        if (e < E) {
            int src = ei[e];
            int dst = ei[(size_t)E + e];
            int b = dst >> BKT_SHIFT;
            bkt[k] = b;
            val[k] = ((u32)src << BKT_SHIFT) | (u32)(dst & (BKT_NODES - 1));
            atomicAdd(&hcnt[b], 1);
        }
    }
    __syncthreads();
    {
        int c = hcnt[tid];
        if (c > 0) hbase[tid] = atomicAdd(&gcur[tid], c);
        hcnt[tid] = 0;
    }
    __syncthreads();
    #pragma unroll
    for (int k = 0; k < 16; ++k) {
        if (bkt[k] >= 0) {
            int b = bkt[k];
            int r = atomicAdd(&hcnt[b], 1);
            int off = hbase[b] + r;
            if (off < BKT_CAP)
                ebuf[(size_t)b * BKT_CAP + off] = val[k];
        }
    }
}

__global__ __launch_bounds__(256) void bucket_csr_kernel(
    const int* __restrict__ gcur, const u32* __restrict__ ebuf,
    int* __restrict__ row_beg, int* __restrict__ degN,
    int* __restrict__ col, int n) {
    __shared__ int deg_l[BKT_NODES];
    __shared__ int pre_l[BKT_NODES];
    __shared__ int cur_l[BKT_NODES];
    __shared__ int wsum[4];
    const int tid = threadIdx.x;
    const int lane = tid & 63, wid = tid >> 6;
    const int b = blockIdx.x;
    const int node0 = b << BKT_SHIFT;
    int cnt = gcur[b];
    if (cnt > BKT_CAP) cnt = BKT_CAP;
    const size_t ebase = (size_t)b * BKT_CAP;

    deg_l[tid] = 0; deg_l[tid + 256] = 0;
    cur_l[tid] = 0; cur_l[tid + 256] = 0;
    __syncthreads();

    for (int i = tid; i < cnt; i += 256)
        atomicAdd(&deg_l[ebuf[ebase + i] & (BKT_NODES - 1)], 1);
    __syncthreads();

    int v0 = deg_l[2 * tid], v1 = deg_l[2 * tid + 1];
    int s = v0 + v1, inc = s;
    #pragma unroll
    for (int d = 1; d < 64; d <<= 1) {
        int t = __shfl_up(inc, d, 64);
        if (lane >= d) inc += t;
    }
    if (lane == 63) wsum[wid] = inc;
    __syncthreads();
    int woff = 0;
    for (int w = 0; w < wid; ++w) woff += wsum[w];
    int ex = woff + (inc - s);
    pre_l[2 * tid] = ex;
    pre_l[2 * tid + 1] = ex + v0;
    __syncthreads();

    #pragma unroll
    for (int p = 0; p < 2; ++p) {
        int idx = tid + p * 256;
        int node = node0 + idx;
        if (node < n) {
            row_beg[node] = (int)ebase + pre_l[idx];
            degN[node]    = deg_l[idx];
        }
    }

    for (int i = tid; i < cnt; i += 256) {
        u32 v = ebuf[ebase + i];
        int d = v & (BKT_NODES - 1);
        int r = atomicAdd(&cur_l[d], 1);
        col[ebase + pre_l[d] + r] = (int)(v >> BKT_SHIFT);
    }
}

// ---------------- weight prep: Wt[o][k] split bf16 hi/lo, k = [w_l | w_r] ----------------

__global__ void build_wt_kernel(const float* __restrict__ wl,
                                const float* __restrict__ wr,
                                u16* __restrict__ wth, u16* __restrict__ wtl) {
    int idx = blockIdx.x * blockDim.x + threadIdx.x;
    if (idx >= 128 * 256) return;
    int o = idx >> 8, k = idx & 255;
    float v = (k < 128) ? wl[o * 128 + k] : wr[o * 128 + (k - 128)];
    u16 hi = f2bf(v);
    wth[idx] = hi;
    wtl[idx] = f2bf(v - bf2f(hi));
}

// ---------------- fp32 -> {bf16, fp8} tables ----------------

__global__ __launch_bounds__(256) void to_conv_kernel(
    const float* __restrict__ in, u16* __restrict__ outh,
    u8* __restrict__ outq, int n4) {
    int stride = gridDim.x * blockDim.x;
    for (int i = blockIdx.x * blockDim.x + threadIdx.x; i < n4; i += stride) {
        float4 v = *(const float4*)&in[(size_t)i * 4];
        ushort4 o;
        o.x = f2bf(v.x); o.y = f2bf(v.y); o.z = f2bf(v.z); o.w = f2bf(v.w);
        *(ushort4*)&outh[(size_t)i * 4] = o;
        u32 q = (u32)f2q(v.x) | ((u32)f2q(v.y) << 8) |
                ((u32)f2q(v.z) << 16) | ((u32)f2q(v.w) << 24);
        *(u32*)&outq[(size_t)i * 4] = q;
    }
}

// ---------------- FUSED: fp8 gather-mean + W-resident MFMA GEMM ----------------
// Per tile of 16 nodes: phase 1 = fp8 gather (16 lanes/node, fp32 accum) ->
// bf16 LDS tile [16][136]; phase 2 = 32 MFMA/wave (A=W pinned resident,
// B=X frags: agg from LDS, self prefetched from global) + packed epilogue.
// Grid-stride over 6250 tiles, 512 blocks (W loaded ONCE per wave — fixes
// R8's fusion failure, which re-read W per block: 819 MB). Eliminates the
// aggh HBM round-trip (51 MB/layer) and one dispatch per layer.

__device__ inline void accumq(float acc[8], uint2 u) {
    f32x2 a;
    a = dq2<false>(u.x); acc[0] += a.x; acc[1] += a.y;
    a = dq2<true >(u.x); acc[2] += a.x; acc[3] += a.y;
    a = dq2<false>(u.y); acc[4] += a.x; acc[5] += a.y;
    a = dq2<true >(u.y); acc[6] += a.x; acc[7] += a.y;
}

__global__ __launch_bounds__(256, 2) void fused_agg_gemm_kernel(
    const u8* __restrict__ gatherq,      // fp8 gather table (xq or hq)
    const u16* __restrict__ selfh,       // bf16 self table (xh or hh)
    const int* __restrict__ row_beg, const int* __restrict__ degN,
    const int* __restrict__ col,
    const u16* __restrict__ wth, const u16* __restrict__ wtl,
    const float* __restrict__ bias,
    float* __restrict__ outF, u16* __restrict__ outH, u8* __restrict__ outQ,
    int n, int do_relu) {
    __shared__ u16 Ah[16][136];          // bf16 agg tile, 272B rows (b128 floor)
    const int tid  = threadIdx.x;
    const int lane = tid & 63;
    const int wid  = tid >> 6;           // outdim strip [wid*32, wid*32+32)
    const int rr = lane & 15, kb = lane >> 4;
    const int ob0 = wid * 32;
    const int ntiles = (n + 15) / 16;

    // ---- W prologue (A operand): 32 frags, pinned resident ----
    bf16x8 WH0[8], WL0[8], WH1[8], WL1[8];
    {
        const u16* h0 = &wth[(size_t)(ob0 + rr) * 256];
        const u16* l0 = &wtl[(size_t)(ob0 + rr) * 256];
        const u16* h1 = &wth[(size_t)(ob0 + 16 + rr) * 256];
        const u16* l1 = &wtl[(size_t)(ob0 + 16 + rr) * 256];
        #pragma unroll
        for (int ks = 0; ks < 8; ++ks) {
            WH0[ks] = *(const bf16x8*)&h0[ks * 32 + kb * 8];
            WL0[ks] = *(const bf16x8*)&l0[ks * 32 + kb * 8];
            WH1[ks] = *(const bf16x8*)&h1[ks * 32 + kb * 8];
            WL1[ks] = *(const bf16x8*)&l1[ks * 32 + kb * 8];
        }
        #pragma unroll
        for (int ks = 0; ks < 8; ++ks)
            asm volatile("" : "+v"(WH0[ks]), "+v"(WL0[ks]),
                              "+v"(WH1[ks]), "+v"(WL1[ks]));
    }
    const float4 bb0 = *(const float4*)&bias[ob0 + kb * 4];
    const float4 bb1 = *(const float4*)&bias[ob0 + 16 + kb * 4];

    for (int t = blockIdx.x; t < ntiles; t += gridDim.x) {
        // ---- self-side prefetch (flies under the gather) ----
        bf16x8 XS[4];
        {
            int row = t * 16 + rr;
            if (row >= n) row = n - 1;
            const u16* sf = &selfh[(size_t)row * NDIM];
            #pragma unroll
            for (int ks = 0; ks < 4; ++ks)
                XS[ks] = *(const bf16x8*)&sf[ks * 32 + kb * 8];
        }

        // ---- phase 1: fp8 gather-mean for 16 nodes (thread = (nl, l)) ----
        {
            const int nl = tid >> 4, l = tid & 15;   // node-local, dim group
            const int node = t * 16 + nl;
            float acc[8] = {0.f, 0.f, 0.f, 0.f, 0.f, 0.f, 0.f, 0.f};
            if (node < n) {
                int beg = row_beg[node];
                int dg  = degN[node];
                int end = beg + dg;
                int j = beg;
                for (; j + 8 <= end; j += 8) {
                    int s[8];
                    #pragma unroll
                    for (int q = 0; q < 8; ++q) s[q] = col[j + q];
                    uint2 u[8];
                    #pragma unroll
                    for (int q = 0; q < 8; ++q)
                        u[q] = *(const uint2*)&gatherq[(size_t)s[q] * NDIM + l * 8];
                    #pragma unroll
                    for (int q = 0; q < 8; ++q) accumq(acc, u[q]);
                }
                if (j + 4 <= end) {
                    int s[4];
                    #pragma unroll
                    for (int q = 0; q < 4; ++q) s[q] = col[j + q];
                    uint2 u[4];
                    #pragma unroll
                    for (int q = 0; q < 4; ++q)
                        u[q] = *(const uint2*)&gatherq[(size_t)s[q] * NDIM + l * 8];
                    #pragma unroll
                    for (int q = 0; q < 4; ++q) accumq(acc, u[q]);
                    j += 4;
                }
                for (; j < end; ++j) {
                    uint2 u = *(const uint2*)&gatherq[(size_t)col[j] * NDIM + l * 8];
                    accumq(acc, u);
                }
                float inv = (dg > 0) ? 1.0f / (float)dg : 0.f;
                #pragma unroll
                for (int q = 0; q < 8; ++q) acc[q] *= inv;
            }
            u32 w0 = (u32)f2bf(acc[0]) | ((u32)f2bf(acc[1]) << 16);
            u32 w1 = (u32)f2bf(acc[2]) | ((u32)f2bf(acc[3]) << 16);
            u32 w2 = (u32)f2bf(acc[4]) | ((u32)f2bf(acc[5]) << 16);
            u32 w3 = (u32)f2bf(acc[6]) | ((u32)f2bf(acc[7]) << 16);
            *(uint4*)&Ah[nl][l * 8] = make_uint4(w0, w1, w2, w3);
        }
        __syncthreads();

        // ---- phase 2: 32 MFMA (A=W resident, B=X) + packed epilogue ----
        {
            bf16x8 XA[4];
            #pragma unroll
            for (int ks = 0; ks < 4; ++ks)
                XA[ks] = *(const bf16x8*)&Ah[rr][ks * 32 + kb * 8];

            f32x4 acc0 = (f32x4){0.f, 0.f, 0.f, 0.f};
            f32x4 acc1 = (f32x4){0.f, 0.f, 0.f, 0.f};
            #pragma unroll
            for (int ks = 0; ks < 4; ++ks) {
                acc0 = __builtin_amdgcn_mfma_f32_16x16x32_bf16(WH0[ks], XA[ks], acc0, 0, 0, 0);
                acc0 = __builtin_amdgcn_mfma_f32_16x16x32_bf16(WL0[ks], XA[ks], acc0, 0, 0, 0);
                acc1 = __builtin_amdgcn_mfma_f32_16x16x32_bf16(WH1[ks], XA[ks], acc1, 0, 0, 0);
                acc1 = __builtin_amdgcn_mfma_f32_16x16x32_bf16(WL1[ks], XA[ks], acc1, 0, 0, 0);
            }
            #pragma unroll
            for (int ks = 0; ks < 4; ++ks) {
                acc0 = __builtin_amdgcn_mfma_f32_16x16x32_bf16(WH0[4 + ks], XS[ks], acc0, 0, 0, 0);
                acc0 = __builtin_amdgcn_mfma_f32_16x16x32_bf16(WL0[4 + ks], XS[ks], acc0, 0, 0, 0);
                acc1 = __builtin_amdgcn_mfma_f32_16x16x32_bf16(WH1[4 + ks], XS[ks], acc1, 0, 0, 0);
                acc1 = __builtin_amdgcn_mfma_f32_16x16x32_bf16(WL1[4 + ks], XS[ks], acc1, 0, 0, 0);
            }

            int node = t * 16 + rr;       // D col = lane&15 = rr
            if (node < n) {
                float v0[4], v1[4];
                #pragma unroll
                for (int r = 0; r < 4; ++r) {
                    v0[r] = acc0[r] + ((const float*)&bb0)[r];
                    v1[r] = acc1[r] + ((const float*)&bb1)[r];
                    if (do_relu) { v0[r] = fmaxf(v0[r], 0.f); v1[r] = fmaxf(v1[r], 0.f); }
                }
                const size_t base = (size_t)node * NDIM;
                const int oA = ob0 + kb * 4;          // D row = kb*4 + r
                const int oB = ob0 + 16 + kb * 4;
                if (outF) {
                    *(float4*)&outF[base + oA] = make_float4(v0[0], v0[1], v0[2], v0[3]);
                    *(float4*)&outF[base + oB] = make_float4(v1[0], v1[1], v1[2], v1[3]);
                }
                if (outH) {
                    *(ushort4*)&outH[base + oA] =
                        make_ushort4(f2bf(v0[0]), f2bf(v0[1]), f2bf(v0[2]), f2bf(v0[3]));
                    *(ushort4*)&outH[base + oB] =
                        make_ushort4(f2bf(v1[0]), f2bf(v1[1]), f2bf(v1[2]), f2bf(v1[3]));
                }
                if (outQ) {
                    *(u32*)&outQ[base + oA] = (u32)f2q(v0[0]) | ((u32)f2q(v0[1]) << 8) |
                                              ((u32)f2q(v0[2]) << 16) | ((u32)f2q(v0[3]) << 24);
                    *(u32*)&outQ[base + oB] = (u32)f2q(v1[0]) | ((u32)f2q(v1[1]) << 8) |
                                              ((u32)f2q(v1[2]) << 16) | ((u32)f2q(v1[3]) << 24);
                }
            }
        }
        __syncthreads();   // LDS reads done before next tile's writes
    }
}

// ---------------- launch ----------------

extern "C" void kernel_launch(void* const* d_in, const int* in_sizes, int n_in,
                              void* d_out, int out_size, void* d_ws, size_t ws_size,
                              hipStream_t stream) {
    const float* x    = (const float*)d_in[0];
    const int*   ei   = (const int*)d_in[1];
    const float* w1_l = (const float*)d_in[2];
    const float* b1   = (const float*)d_in[3];
    const float* w1_r = (const float*)d_in[4];
    const float* w2_l = (const float*)d_in[5];
    const float* b2   = (const float*)d_in[6];
    const float* w2_r = (const float*)d_in[7];
    const int N = in_sizes[0] / NDIM;
    const int E = in_sizes[1] / 2;
    float* out = (float*)d_out;

    const int NB = (N + BKT_NODES - 1) >> BKT_SHIFT;

    char* ws = (char*)d_ws;
    size_t off = 0;
    auto take = [&](size_t bytes) -> char* {
        char* p = ws + off;
        off += (bytes + 255) & ~(size_t)255;
        return p;
    };
    int* row_beg = (int*)take((size_t)N * 4);
    int* degN    = (int*)take((size_t)N * 4);
    int* gcur    = (int*)take((size_t)NB * 4);
    u32* ebuf    = (u32*)take((size_t)NB * BKT_CAP * 4);
    int* colA    = (int*)take((size_t)NB * BKT_CAP * 4);
    u16* wt1h    = (u16*)take(128 * 256 * 2);
    u16* wt1l    = (u16*)take(128 * 256 * 2);
    u16* wt2h    = (u16*)take(128 * 256 * 2);
    u16* wt2l    = (u16*)take(128 * 256 * 2);
    u16* hh      = (u16*)take((size_t)N * NDIM * 2);
    u8*  hq      = (u8*)take((size_t)N * NDIM);      // in ws: layer-2 reads hq WHILE writing outF
    // d_out scratch (dead before layer-2's outF writes): xh bf16 + xq fp8
    u16* xh = (u16*)d_out;
    u8*  xq = (u8*)d_out + (size_t)N * NDIM * 2;

    (void)hipMemsetAsync(gcur, 0, (size_t)NB * 4, stream);
    partition_kernel<<<(E + PART_CHUNK - 1) / PART_CHUNK, 256, 0, stream>>>(ei, E, gcur, ebuf);
    bucket_csr_kernel<<<NB, 256, 0, stream>>>(gcur, ebuf, row_beg, degN, colA, N);
    build_wt_kernel<<<128, 256, 0, stream>>>(w1_l, w1_r, wt1h, wt1l);
    build_wt_kernel<<<128, 256, 0, stream>>>(w2_l, w2_r, wt2h, wt2l);
    to_conv_kernel<<<2048, 256, 0, stream>>>(x, xh, xq, N * NDIM / 4);

    const int gblk = 512;   // all blocks co-resident (2/CU); W loaded once per wave
    // layer 1: h = relu([mean(x) | x] @ Wt1 + b1) -> hh (bf16, ws) + hq (fp8, ws)
    fused_agg_gemm_kernel<<<gblk, 256, 0, stream>>>(xq, xh, row_beg, degN, colA,
                                                    wt1h, wt1l, b1,
                                                    (float*)0, hh, hq, N, 1);
    // layer 2: out = [mean(h) | h] @ Wt2 + b2 -> d_out (fp32)
    fused_agg_gemm_kernel<<<gblk, 256, 0, stream>>>(hq, hh, row_beg, degN, colA,
                                                    wt2h, wt2l, b2,
                                                    out, (u16*)0, (u8*)0, N, 0);
}

// Round 22
// 187.576 us; speedup vs baseline: 1.3652x; 1.3652x over previous
//
#include <hip/hip_runtime.h>

#define NDIM 128
#define BKT_SHIFT 9            // 512 nodes per bucket
#define BKT_NODES 512
#define BKT_CAP   12288        // edges capacity per bucket (mean ~8163)
#define PART_CHUNK 4096        // edges per block in partition kernel

typedef unsigned short u16;
typedef unsigned char u8;
typedef unsigned int u32;
typedef __attribute__((ext_vector_type(8))) short bf16x8;
typedef __attribute__((ext_vector_type(4))) float f32x4;
typedef __attribute__((ext_vector_type(2))) float f32x2;

__device__ inline u16 f2bf(float f) {
    u32 u = __float_as_uint(f);
    u += 0x7fffu + ((u >> 16) & 1u);   // RNE
    return (u16)(u >> 16);
}
__device__ inline float bf2f(u16 h) { return __uint_as_float((u32)h << 16); }

// float -> fp8 e4m3fn (OCP), RNE, saturating.
__device__ inline u8 f2q(float f) {
    u32 u = __float_as_uint(f);
    u32 s = (u >> 24) & 0x80u;
    float a = __uint_as_float(u & 0x7fffffffu);
    if (a < 0.015625f)
        return (u8)(s | (u32)__float2int_rn(a * 512.f));
    if (a >= 448.f) return (u8)(s | 0x7Eu);
    u32 ur = (u & 0x7fffffffu) + 0x7FFFFu + ((u >> 20) & 1u);
    int e = (int)(ur >> 23) - 127;
    u32 man = (ur >> 20) & 7u;
    u32 r = ((u32)(e + 7) << 3) | man;
    if (r > 0x7Eu) r = 0x7Eu;
    return (u8)(s | r);
}

#if __has_builtin(__builtin_amdgcn_cvt_pk_f32_fp8)
template<bool HI>
__device__ inline f32x2 dq2(u32 w) {
    return __builtin_amdgcn_cvt_pk_f32_fp8((int)w, HI);
}
#else
__device__ inline float dq1(u32 b) {
    int e = (b >> 3) & 15, m = b & 7, s = (b >> 7) & 1;
    int norm = e ? 1 : 0;
    float f = (float)(m + (norm << 3));
    float sc = __uint_as_float((u32)(((e ? e : 1) - 10) + 127) << 23);
    float v = f * sc;
    return s ? -v : v;
}
template<bool HI>
__device__ inline f32x2 dq2(u32 w) {
    u32 sh = HI ? 16 : 0;
    f32x2 r; r.x = dq1((w >> sh) & 0xff); r.y = dq1((w >> (sh + 8)) & 0xff);
    return r;
}
#endif

__device__ __forceinline__ void gl_lds16(const void* g, void* l) {
    // async global->LDS, 16B/lane; LDS arg = wave-uniform base (HW adds lane*16),
    // global arg = per-lane address.
    __builtin_amdgcn_global_load_lds(
        (const __attribute__((address_space(1))) void*)g,
        (__attribute__((address_space(3))) void*)l, 16, 0, 0);
}

// ---------------- bucketed CSR build (unchanged — working) ----------------

__global__ __launch_bounds__(256) void partition_kernel(
    const int* __restrict__ ei, int E,
    int* __restrict__ gcur, u32* __restrict__ ebuf) {
    __shared__ int hcnt[256];
    __shared__ int hbase[256];
    const int tid = threadIdx.x;
    const int base = blockIdx.x * PART_CHUNK;
    hcnt[tid] = 0;
    __syncthreads();

    u32 val[16];
    int bkt[16];
    #pragma unroll
    for (int k = 0; k < 16; ++k) {
        int e = base + k * 256 + tid;
        bkt[k] = -1;
        if (e < E) {
            int src = ei[e];
            int dst = ei[(size_t)E + e];
            int b = dst >> BKT_SHIFT;
            bkt[k] = b;
            val[k] = ((u32)src << BKT_SHIFT) | (u32)(dst & (BKT_NODES - 1));
            atomicAdd(&hcnt[b], 1);
        }
    }
    __syncthreads();
    {
        int c = hcnt[tid];
        if (c > 0) hbase[tid] = atomicAdd(&gcur[tid], c);
        hcnt[tid] = 0;
    }
    __syncthreads();
    #pragma unroll
    for (int k = 0; k < 16; ++k) {
        if (bkt[k] >= 0) {
            int b = bkt[k];
            int r = atomicAdd(&hcnt[b], 1);
            int off = hbase[b] + r;
            if (off < BKT_CAP)
                ebuf[(size_t)b * BKT_CAP + off] = val[k];
        }
    }
}

__global__ __launch_bounds__(256) void bucket_csr_kernel(
    const int* __restrict__ gcur, const u32* __restrict__ ebuf,
    int* __restrict__ row_beg, int* __restrict__ degN,
    int* __restrict__ col, int n) {
    __shared__ int deg_l[BKT_NODES];
    __shared__ int pre_l[BKT_NODES];
    __shared__ int cur_l[BKT_NODES];
    __shared__ int wsum[4];
    const int tid = threadIdx.x;
    const int lane = tid & 63, wid = tid >> 6;
    const int b = blockIdx.x;
    const int node0 = b << BKT_SHIFT;
    int cnt = gcur[b];
    if (cnt > BKT_CAP) cnt = BKT_CAP;
    const size_t ebase = (size_t)b * BKT_CAP;

    deg_l[tid] = 0; deg_l[tid + 256] = 0;
    cur_l[tid] = 0; cur_l[tid + 256] = 0;
    __syncthreads();

    for (int i = tid; i < cnt; i += 256)
        atomicAdd(&deg_l[ebuf[ebase + i] & (BKT_NODES - 1)], 1);
    __syncthreads();

    int v0 = deg_l[2 * tid], v1 = deg_l[2 * tid + 1];
    int s = v0 + v1, inc = s;
    #pragma unroll
    for (int d = 1; d < 64; d <<= 1) {
        int t = __shfl_up(inc, d, 64);
        if (lane >= d) inc += t;
    }
    if (lane == 63) wsum[wid] = inc;
    __syncthreads();
    int woff = 0;
    for (int w = 0; w < wid; ++w) woff += wsum[w];
    int ex = woff + (inc - s);
    pre_l[2 * tid] = ex;
    pre_l[2 * tid + 1] = ex + v0;
    __syncthreads();

    #pragma unroll
    for (int p = 0; p < 2; ++p) {
        int idx = tid + p * 256;
        int node = node0 + idx;
        if (node < n) {
            row_beg[node] = (int)ebase + pre_l[idx];
            degN[node]    = deg_l[idx];
        }
    }

    for (int i = tid; i < cnt; i += 256) {
        u32 v = ebuf[ebase + i];
        int d = v & (BKT_NODES - 1);
        int r = atomicAdd(&cur_l[d], 1);
        col[ebase + pre_l[d] + r] = (int)(v >> BKT_SHIFT);
    }
}

// ---------------- weight prep: Wt[o][k] split bf16 hi/lo, k = [w_l | w_r] ----------------

__global__ void build_wt_kernel(const float* __restrict__ wl,
                                const float* __restrict__ wr,
                                u16* __restrict__ wth, u16* __restrict__ wtl) {
    int idx = blockIdx.x * blockDim.x + threadIdx.x;
    if (idx >= 128 * 256) return;
    int o = idx >> 8, k = idx & 255;
    float v = (k < 128) ? wl[o * 128 + k] : wr[o * 128 + (k - 128)];
    u16 hi = f2bf(v);
    wth[idx] = hi;
    wtl[idx] = f2bf(v - bf2f(hi));
}

// ---------------- fp32 -> {bf16, fp8} tables ----------------

__global__ __launch_bounds__(256) void to_conv_kernel(
    const float* __restrict__ in, u16* __restrict__ outh,
    u8* __restrict__ outq, int n4) {
    int stride = gridDim.x * blockDim.x;
    for (int i = blockIdx.x * blockDim.x + threadIdx.x; i < n4; i += stride) {
        float4 v = *(const float4*)&in[(size_t)i * 4];
        ushort4 o;
        o.x = f2bf(v.x); o.y = f2bf(v.y); o.z = f2bf(v.z); o.w = f2bf(v.w);
        *(ushort4*)&outh[(size_t)i * 4] = o;
        u32 q = (u32)f2q(v.x) | ((u32)f2q(v.y) << 8) |
                ((u32)f2q(v.z) << 16) | ((u32)f2q(v.w) << 24);
        *(u32*)&outq[(size_t)i * 4] = q;
    }
}

// ---------------- mean aggregation: fp8 gather, fp32 accum, bf16 out ----------------
// (separate kernel again — R21 proved gather needs 6250-block TLP)

__device__ inline void accumq(float acc[8], uint2 u) {
    f32x2 a;
    a = dq2<false>(u.x); acc[0] += a.x; acc[1] += a.y;
    a = dq2<true >(u.x); acc[2] += a.x; acc[3] += a.y;
    a = dq2<false>(u.y); acc[4] += a.x; acc[5] += a.y;
    a = dq2<true >(u.y); acc[6] += a.x; acc[7] += a.y;
}

__global__ __launch_bounds__(256) void aggregate_fp8_kernel(
    const u8* __restrict__ feat, const int* __restrict__ row_beg,
    const int* __restrict__ degN, const int* __restrict__ col,
    u16* __restrict__ aggh, int n) {
    int node = blockIdx.x * 16 + (threadIdx.x >> 4);
    if (node >= n) return;
    int l = threadIdx.x & 15;   // dims [8l, 8l+8)
    int beg = row_beg[node];
    int dg  = degN[node];
    int end = beg + dg;
    float acc[8] = {0.f, 0.f, 0.f, 0.f, 0.f, 0.f, 0.f, 0.f};
    int j = beg;
    for (; j + 8 <= end; j += 8) {
        int s[8];
        #pragma unroll
        for (int q = 0; q < 8; ++q) s[q] = col[j + q];
        uint2 u[8];
        #pragma unroll
        for (int q = 0; q < 8; ++q)
            u[q] = *(const uint2*)&feat[(size_t)s[q] * NDIM + l * 8];
        #pragma unroll
        for (int q = 0; q < 8; ++q) accumq(acc, u[q]);
    }
    if (j + 4 <= end) {
        int s[4];
        #pragma unroll
        for (int q = 0; q < 4; ++q) s[q] = col[j + q];
        uint2 u[4];
        #pragma unroll
        for (int q = 0; q < 4; ++q)
            u[q] = *(const uint2*)&feat[(size_t)s[q] * NDIM + l * 8];
        #pragma unroll
        for (int q = 0; q < 4; ++q) accumq(acc, u[q]);
        j += 4;
    }
    for (; j < end; ++j) {
        uint2 u = *(const uint2*)&feat[(size_t)col[j] * NDIM + l * 8];
        accumq(acc, u);
    }
    float inv = (dg > 0) ? 1.0f / (float)dg : 0.f;
    u16 hs[8];
    #pragma unroll
    for (int q = 0; q < 8; ++q) hs[q] = f2bf(acc[q] * inv);
    *(ushort4*)&aggh[(size_t)node * NDIM + l * 8]     = make_ushort4(hs[0], hs[1], hs[2], hs[3]);
    *(ushort4*)&aggh[(size_t)node * NDIM + l * 8 + 4] = make_ushort4(hs[4], hs[5], hs[6], hs[7]);
}

// ---------------- W-resident MFMA GEMM with LDS-staged A (async, dbuf) ----------------
// R21 insight: the 4 column-strip waves each re-loaded the same 16 A-rows ->
// 4x redundant request traffic; 16 scattered dwordx4/wave/tile was the latency
// wall no scheduling trick fixed (R16-R20 nulls). Now ONE cooperative async
// stage per tile (global_load_lds, 8KB: agg 4KB + self 4KB, perfectly linear),
// double-buffered; all 4 waves read fragments from LDS. Requests 4x lower,
// loads decoupled from consumption (m97 pattern: stage t+1 under compute t).
// XOR-swizzle pair (rule #21): inverse-swizzled GLOBAL source + swizzled LDS
// read, linear LDS dest. swz(a) = a ^ (((a>>8)&7)<<4)  (involution, 16B gran).

__global__ __launch_bounds__(256, 2) void gemm_wstat_lds_kernel(
    const u16* __restrict__ aggh, const u16* __restrict__ selfh,
    const u16* __restrict__ wth, const u16* __restrict__ wtl,
    const float* __restrict__ bias,
    float* __restrict__ outF, u16* __restrict__ outH, u8* __restrict__ outQ,
    int M, int do_relu) {
    __shared__ u16 Abuf[2][4096];        // per buf: [0,4KB) agg tile, [4KB,8KB) self tile
    const int tid  = threadIdx.x;
    const int lane = tid & 63;
    const int wid  = tid >> 6;           // outdim strip [wid*32, wid*32+32)
    const int rr = lane & 15, kb = lane >> 4;
    const int ob0 = wid * 32;
    const int ntiles = (M + 15) / 16;
    const int stride = gridDim.x;

    // ---- W prologue (A operand): 32 frags, pinned resident ----
    bf16x8 WH0[8], WL0[8], WH1[8], WL1[8];
    {
        const u16* h0 = &wth[(size_t)(ob0 + rr) * 256];
        const u16* l0 = &wtl[(size_t)(ob0 + rr) * 256];
        const u16* h1 = &wth[(size_t)(ob0 + 16 + rr) * 256];
        const u16* l1 = &wtl[(size_t)(ob0 + 16 + rr) * 256];
        #pragma unroll
        for (int ks = 0; ks < 8; ++ks) {
            WH0[ks] = *(const bf16x8*)&h0[ks * 32 + kb * 8];
            WL0[ks] = *(const bf16x8*)&l0[ks * 32 + kb * 8];
            WH1[ks] = *(const bf16x8*)&h1[ks * 32 + kb * 8];
            WL1[ks] = *(const bf16x8*)&l1[ks * 32 + kb * 8];
        }
        #pragma unroll
        for (int ks = 0; ks < 8; ++ks)
            asm volatile("" : "+v"(WH0[ks]), "+v"(WL0[ks]),
                              "+v"(WH1[ks]), "+v"(WL1[ks]));
    }
    const float4 bb0 = *(const float4*)&bias[ob0 + kb * 4];
    const float4 bb1 = *(const float4*)&bias[ob0 + 16 + kb * 4];

    // per-lane inverse-swizzled global chunk index for each of this wave's 2 issues
    // chunk c in [0,512): region = c>>8 (0 agg, 1 self); cc = c&255;
    // src chunk within region = cc ^ ((cc>>4)&7)
    int srcoff[2];   // byte offset within the region's 4KB tile
    int reg_[2];     // region select
    int ldsoff[2];   // wave-uniform LDS chunk base (u16 index)
    #pragma unroll
    for (int is = 0; is < 2; ++is) {
        int c = wid * 128 + is * 64 + lane;
        int cc = c & 255;
        int sc = cc ^ ((cc >> 4) & 7);
        srcoff[is] = sc * 16;
        reg_[is]   = c >> 8;
        ldsoff[is] = (wid * 128 + is * 64) * 8;   // u16 units (chunk*16B/2)
    }

    auto stage = [&](int buf, int t) {
        const char* ga = (const char*)aggh  + (size_t)t * 4096;
        const char* gs = (const char*)selfh + (size_t)t * 4096;
        #pragma unroll
        for (int is = 0; is < 2; ++is) {
            const char* g = (reg_[is] ? gs : ga) + srcoff[is];
            gl_lds16(g, &Abuf[buf][ldsoff[is]]);
        }
    };

    auto computeStore = [&](int buf, int t) {
        const char* sb = (const char*)&Abuf[buf][0];
        const int sw = (rr & 7) << 4;
        bf16x8 XA[4], XS[4];
        #pragma unroll
        for (int ks = 0; ks < 4; ++ks) {
            int a = rr * 256 + ks * 64 + kb * 16;
            XA[ks] = *(const bf16x8*)(sb + (a ^ sw));
            XS[ks] = *(const bf16x8*)(sb + 4096 + (a ^ sw));
        }
        f32x4 acc0 = (f32x4){0.f, 0.f, 0.f, 0.f};
        f32x4 acc1 = (f32x4){0.f, 0.f, 0.f, 0.f};
        #pragma unroll
        for (int ks = 0; ks < 4; ++ks) {
            acc0 = __builtin_amdgcn_mfma_f32_16x16x32_bf16(WH0[ks], XA[ks], acc0, 0, 0, 0);
            acc0 = __builtin_amdgcn_mfma_f32_16x16x32_bf16(WL0[ks], XA[ks], acc0, 0, 0, 0);
            acc1 = __builtin_amdgcn_mfma_f32_16x16x32_bf16(WH1[ks], XA[ks], acc1, 0, 0, 0);
            acc1 = __builtin_amdgcn_mfma_f32_16x16x32_bf16(WL1[ks], XA[ks], acc1, 0, 0, 0);
        }
        #pragma unroll
        for (int ks = 0; ks < 4; ++ks) {
            acc0 = __builtin_amdgcn_mfma_f32_16x16x32_bf16(WH0[4 + ks], XS[ks], acc0, 0, 0, 0);
            acc0 = __builtin_amdgcn_mfma_f32_16x16x32_bf16(WL0[4 + ks], XS[ks], acc0, 0, 0, 0);
            acc1 = __builtin_amdgcn_mfma_f32_16x16x32_bf16(WH1[4 + ks], XS[ks], acc1, 0, 0, 0);
            acc1 = __builtin_amdgcn_mfma_f32_16x16x32_bf16(WL1[4 + ks], XS[ks], acc1, 0, 0, 0);
        }
        int node = t * 16 + rr;       // D col = lane&15 = rr
        if (node < M) {
            float v0[4], v1[4];
            #pragma unroll
            for (int r = 0; r < 4; ++r) {
                v0[r] = acc0[r] + ((const float*)&bb0)[r];
                v1[r] = acc1[r] + ((const float*)&bb1)[r];
                if (do_relu) { v0[r] = fmaxf(v0[r], 0.f); v1[r] = fmaxf(v1[r], 0.f); }
            }
            const size_t base = (size_t)node * NDIM;
            const int oA = ob0 + kb * 4;          // D row = kb*4 + r
            const int oB = ob0 + 16 + kb * 4;
            if (outF) {
                *(float4*)&outF[base + oA] = make_float4(v0[0], v0[1], v0[2], v0[3]);
                *(float4*)&outF[base + oB] = make_float4(v1[0], v1[1], v1[2], v1[3]);
            }
            if (outH) {
                *(ushort4*)&outH[base + oA] =
                    make_ushort4(f2bf(v0[0]), f2bf(v0[1]), f2bf(v0[2]), f2bf(v0[3]));
                *(ushort4*)&outH[base + oB] =
                    make_ushort4(f2bf(v1[0]), f2bf(v1[1]), f2bf(v1[2]), f2bf(v1[3]));
            }
            if (outQ) {
                *(u32*)&outQ[base + oA] = (u32)f2q(v0[0]) | ((u32)f2q(v0[1]) << 8) |
                                          ((u32)f2q(v0[2]) << 16) | ((u32)f2q(v0[3]) << 24);
                *(u32*)&outQ[base + oB] = (u32)f2q(v1[0]) | ((u32)f2q(v1[1]) << 8) |
                                          ((u32)f2q(v1[2]) << 16) | ((u32)f2q(v1[3]) << 24);
            }
        }
    };

    int t = blockIdx.x;
    if (t >= ntiles) return;
    int cur = 0;
    stage(0, t);
    __syncthreads();                       // drain stage(t), all waves synced
    while (true) {
        int tn = t + stride;
        if (tn < ntiles) stage(cur ^ 1, tn);   // async; flies under compute(t)
        computeStore(cur, t);
        __syncthreads();                   // LDS reads done + stage(tn) drained
        cur ^= 1;
        t = tn;
        if (t >= ntiles) break;
    }
}

// ---------------- launch ----------------

extern "C" void kernel_launch(void* const* d_in, const int* in_sizes, int n_in,
                              void* d_out, int out_size, void* d_ws, size_t ws_size,
                              hipStream_t stream) {
    const float* x    = (const float*)d_in[0];
    const int*   ei   = (const int*)d_in[1];
    const float* w1_l = (const float*)d_in[2];
    const float* b1   = (const float*)d_in[3];
    const float* w1_r = (const float*)d_in[4];
    const float* w2_l = (const float*)d_in[5];
    const float* b2   = (const float*)d_in[6];
    const float* w2_r = (const float*)d_in[7];
    const int N = in_sizes[0] / NDIM;
    const int E = in_sizes[1] / 2;
    float* out = (float*)d_out;

    const int NB = (N + BKT_NODES - 1) >> BKT_SHIFT;

    char* ws = (char*)d_ws;
    size_t off = 0;
    auto take = [&](size_t bytes) -> char* {
        char* p = ws + off;
        off += (bytes + 255) & ~(size_t)255;
        return p;
    };
    int* row_beg = (int*)take((size_t)N * 4);
    int* degN    = (int*)take((size_t)N * 4);
    int* gcur    = (int*)take((size_t)NB * 4);
    u32* ebuf    = (u32*)take((size_t)NB * BKT_CAP * 4);
    int* colA    = (int*)take((size_t)NB * BKT_CAP * 4);
    u16* wt1h    = (u16*)take(128 * 256 * 2);
    u16* wt1l    = (u16*)take(128 * 256 * 2);
    u16* wt2h    = (u16*)take(128 * 256 * 2);
    u16* wt2l    = (u16*)take(128 * 256 * 2);
    u16* aggh    = (u16*)take((size_t)N * NDIM * 2);
    u16* hh      = (u16*)take((size_t)N * NDIM * 2);
    // d_out scratch until gemm2's final overwrite:
    //   xh [0,2NB)  xq [2NB,3NB)  hq [3NB,4NB)   (NB = N*NDIM bytes)
    u16* xh = (u16*)d_out;
    u8*  xq = (u8*)d_out + (size_t)N * NDIM * 2;
    u8*  hq = (u8*)d_out + (size_t)N * NDIM * 3;

    (void)hipMemsetAsync(gcur, 0, (size_t)NB * 4, stream);
    partition_kernel<<<(E + PART_CHUNK - 1) / PART_CHUNK, 256, 0, stream>>>(ei, E, gcur, ebuf);
    bucket_csr_kernel<<<NB, 256, 0, stream>>>(gcur, ebuf, row_beg, degN, colA, N);
    build_wt_kernel<<<128, 256, 0, stream>>>(w1_l, w1_r, wt1h, wt1l);
    build_wt_kernel<<<128, 256, 0, stream>>>(w2_l, w2_r, wt2h, wt2l);
    to_conv_kernel<<<2048, 256, 0, stream>>>(x, xh, xq, N * NDIM / 4);

    const int gblk = 512;
    // layer 1: h = relu([mean(x) | x] @ Wt1 + b1) -> hh (bf16) + hq (fp8)
    aggregate_fp8_kernel<<<(N + 15) / 16, 256, 0, stream>>>(xq, row_beg, degN, colA, aggh, N);
    gemm_wstat_lds_kernel<<<gblk, 256, 0, stream>>>(aggh, xh, wt1h, wt1l, b1,
                                                    (float*)0, hh, hq, N, 1);
    // layer 2: out = [mean(h) | h] @ Wt2 + b2
    aggregate_fp8_kernel<<<(N + 15) / 16, 256, 0, stream>>>(hq, row_beg, degN, colA, aggh, N);
    gemm_wstat_lds_kernel<<<gblk, 256, 0, stream>>>(aggh, hh, wt2h, wt2l, b2,
                                                    out, (u16*)0, (u8*)0, N, 0);
}